// Round 1
// baseline (13003.729 us; speedup 1.0000x reference)
//
#include <hip/hip_runtime.h>
#include <hip/hip_bf16.h>

typedef float f32x4 __attribute__((ext_vector_type(4)));
typedef short short8 __attribute__((ext_vector_type(8)));
typedef __bf16 bf16x8 __attribute__((ext_vector_type(8)));

#define DI __device__ __forceinline__

// Problem sizes
constexpr int Bsz = 64;    // batch
constexpr int Fd  = 1024;  // features == hidden
constexpr int Seq = 256;
constexpr int G4  = 4096;  // 4*H
constexpr int Mrows = Seq * Bsz;  // 16384 GEMM rows, r = s*64 + b

DI float bf2f(unsigned short u) {
  union { unsigned int i; float f; } v; v.i = ((unsigned int)u) << 16; return v.f;
}
DI unsigned short f2bf(float f) {
  union { float ff; unsigned int i; } v; v.ff = f;
  unsigned int x = v.i;
  return (unsigned short)((x + 0x7fffu + ((x >> 16) & 1u)) >> 16);
}
DI float sigm(float x) { return 1.f / (1.f + __expf(-x)); }
DI float tanhfast(float x) {
  float e = __expf(-2.f * fabsf(x));
  float t = (1.f - e) / (1.f + e);
  return x < 0.f ? -t : t;
}
DI f32x4 mfma16(short8 a, short8 b, f32x4 c) {
  return __builtin_amdgcn_mfma_f32_16x16x32_bf16(
      __builtin_bit_cast(bf16x8, a), __builtin_bit_cast(bf16x8, b), c, 0, 0, 0);
}

// ---------- transpose x [B][F][S] f32 -> xs [S][B][F] bf16 (r = s*64+b major) ----------
__global__ void k_tx(const float* __restrict__ x, unsigned short* __restrict__ xs) {
  __shared__ float t[32][33];
  int b = blockIdx.z, f0 = blockIdx.y * 32, s0 = blockIdx.x * 32;
  int tx = threadIdx.x & 31, ty = threadIdx.x >> 5;  // ty 0..7
  const float* src = x + ((size_t)b * Fd + f0) * Seq + s0;
#pragma unroll
  for (int i = 0; i < 32; i += 8)
    t[ty + i][tx] = src[(size_t)(ty + i) * Seq + tx];
  __syncthreads();
#pragma unroll
  for (int i = 0; i < 32; i += 8) {
    int s = s0 + ty + i, f = f0 + tx;
    xs[((size_t)s * Bsz + b) * Fd + f] = f2bf(t[tx][ty + i]);
  }
}

// ---------- transpose-convert [1024][4096] f32 -> [4096][1024] bf16 ----------
__global__ void k_tw(const float* __restrict__ in, unsigned short* __restrict__ out) {
  __shared__ float t[32][33];
  int n0 = blockIdx.x * 32, k0 = blockIdx.y * 32;
  int tx = threadIdx.x & 31, ty = threadIdx.x >> 5;
#pragma unroll
  for (int i = 0; i < 32; i += 8)
    t[ty + i][tx] = in[(size_t)(k0 + ty + i) * G4 + n0 + tx];
  __syncthreads();
#pragma unroll
  for (int i = 0; i < 32; i += 8)
    out[(size_t)(n0 + ty + i) * 1024 + k0 + tx] = f2bf(t[tx][ty + i]);
}

__global__ void k_zero(unsigned int* p, int n) {
  int i = blockIdx.x * 256 + threadIdx.x;
  if (i < n) p[i] = 0u;
}

// ---------- GEMM: C[16384][4096] bf16 = A[16384][1024] x Bt[4096][1024]^T ----------
__launch_bounds__(256, 2)
__global__ void k_gemm(const unsigned short* __restrict__ A,
                       const unsigned short* __restrict__ Bt,
                       unsigned short* __restrict__ C) {
  __shared__ unsigned short a_lds[128 * 64];
  __shared__ unsigned short b_lds[128 * 64];
  int bid = blockIdx.x;
  int tm = bid & 127, tn = bid >> 7;  // 128 m-tiles, 32 n-tiles
  int tid = threadIdx.x, w = tid >> 6, l = tid & 63;
  int wm = w >> 1, wn = w & 1;
  f32x4 acc[4][4] = {};
  const unsigned short* Ab = A + (size_t)(tm * 128) * 1024;
  const unsigned short* Bb = Bt + (size_t)(tn * 128) * 1024;
  for (int kt = 0; kt < 16; ++kt) {
#pragma unroll
    for (int i = 0; i < 4; ++i) {
      int ci = tid + i * 256;     // 0..1023 16B chunks
      int row = ci >> 3;
      int kB = (ci & 7) * 16;     // byte offset in 128B row
      short8 va = *(const short8*)((const char*)(Ab + (size_t)row * 1024 + kt * 64) + kB);
      short8 vb = *(const short8*)((const char*)(Bb + (size_t)row * 1024 + kt * 64) + kB);
      int dst = row * 128 + (kB ^ ((row & 7) << 4));
      *(short8*)((char*)a_lds + dst) = va;
      *(short8*)((char*)b_lds + dst) = vb;
    }
    __syncthreads();
#pragma unroll
    for (int kb = 0; kb < 2; ++kb) {
      short8 af[4], bfv[4];
      int kByte = (kb * 32 + ((l >> 4) << 3)) * 2;
#pragma unroll
      for (int mi = 0; mi < 4; ++mi) {
        int row = wm * 64 + mi * 16 + (l & 15);
        af[mi] = *(const short8*)((const char*)a_lds + row * 128 + (kByte ^ ((row & 7) << 4)));
      }
#pragma unroll
      for (int ni = 0; ni < 4; ++ni) {
        int row = wn * 64 + ni * 16 + (l & 15);
        bfv[ni] = *(const short8*)((const char*)b_lds + row * 128 + (kByte ^ ((row & 7) << 4)));
      }
#pragma unroll
      for (int mi = 0; mi < 4; ++mi)
#pragma unroll
        for (int ni = 0; ni < 4; ++ni)
          acc[mi][ni] = mfma16(af[mi], bfv[ni], acc[mi][ni]);
    }
    __syncthreads();
  }
#pragma unroll
  for (int mi = 0; mi < 4; ++mi)
#pragma unroll
    for (int ni = 0; ni < 4; ++ni)
#pragma unroll
      for (int r = 0; r < 4; ++r) {
        int m = tm * 128 + wm * 64 + mi * 16 + ((l >> 4) << 2) + r;
        int n = tn * 128 + wn * 64 + ni * 16 + (l & 15);
        C[(size_t)m * G4 + n] = f2bf(acc[mi][ni][r]);
      }
}

// ---------- recurrence ----------
// 256 blocks: rg = bid&3 (16 batch rows), jg = bid>>2 (16 hidden cols).
// Wave w = gate w; each wave: 16x16 output tile, K=1024, U frags in VGPRs.
// Sync: per-(rg,jg) monotone tag = number of steps produced. No grid barrier.
__launch_bounds__(256, 1)
__global__ void k_rec(const unsigned short* __restrict__ xs,
                      const unsigned short* __restrict__ xWb,
                      const unsigned short* __restrict__ Ubt,
                      const float* __restrict__ bias,
                      unsigned short* __restrict__ hbuf,  // [2][64][1024] bf16
                      unsigned int* tags,                 // [4][64]
                      float* __restrict__ out) {
  __shared__ unsigned short h_lds[16 * 1024];  // swizzled
  __shared__ float g_lds[16][64];              // [row][gate*16+jj]
  int bid = blockIdx.x;
  int rg = bid & 3, jg = bid >> 2;
  int j0 = jg * 16;
  int tid = threadIdx.x, w = tid >> 6, l = tid & 63;

  // preload U fragments: col n = w*1024 + j0 + (l&15), k = kb*32 + (l>>4)*8
  int ncol = w * 1024 + j0 + (l & 15);
  const unsigned short* Urow = Ubt + (size_t)ncol * 1024;
  short8 ufr[32];
#pragma unroll
  for (int kb = 0; kb < 32; ++kb)
    ufr[kb] = *(const short8*)(Urow + kb * 32 + ((l >> 4) << 3));
  float bias_l = bias[ncol];

  unsigned int* mytags = tags + rg * 64;
  unsigned int* mytag = tags + rg * 64 + jg;

  for (int t = 0; t < Seq; ++t) {
    f32x4 acc = {0.f, 0.f, 0.f, 0.f};
    if (t > 0) {
      if (tid < 64) {
        while (__hip_atomic_load(&mytags[tid], __ATOMIC_RELAXED,
                                 __HIP_MEMORY_SCOPE_AGENT) < (unsigned int)t) {
          __builtin_amdgcn_s_sleep(1);
        }
      }
      __syncthreads();
      __threadfence();  // acquire: invalidate stale L1/L2 before reading peers' h
      const unsigned short* hprev =
          hbuf + (size_t)((t & 1) ^ 1) * (64 * 1024) + (size_t)rg * 16 * 1024;
#pragma unroll
      for (int i = 0; i < 8; ++i) {
        int ci = tid + i * 256;  // 0..2047 16B chunks
        int row = ci >> 7;
        int kB = (ci & 127) * 16;
        short8 v = *(const short8*)((const char*)(hprev + (size_t)row * 1024) + kB);
        *(short8*)((char*)h_lds + row * 2048 + (kB ^ ((row & 7) << 4))) = v;
      }
      __syncthreads();
#pragma unroll
      for (int kb = 0; kb < 32; ++kb) {
        int row = l & 15;
        int kByte = (kb * 32 + ((l >> 4) << 3)) * 2;
        short8 af = *(const short8*)((const char*)h_lds + row * 2048 +
                                     (kByte ^ ((row & 7) << 4)));
        acc = mfma16(af, ufr[kb], acc);
      }
    }
    // gates -> LDS (add xW + bias)
#pragma unroll
    for (int r = 0; r < 4; ++r) {
      int mloc = ((l >> 4) << 2) + r;
      int m = rg * 16 + mloc;  // batch row
      float xw = bf2f(xWb[((size_t)t * 64 + m) * G4 + ncol]);
      g_lds[mloc][w * 16 + (l & 15)] = acc[r] + xw + bias_l;
    }
    __syncthreads();
    // pointwise: thread = (row2 = tid>>4, jj = tid&15)
    {
      int row2 = tid >> 4, jj = tid & 15;
      int b = rg * 16 + row2, j = j0 + jj;
      float iv = g_lds[row2][jj];
      float fv = g_lds[row2][16 + jj];
      float gv = g_lds[row2][32 + jj];
      float ov = g_lds[row2][48 + jj];
      float xt = bf2f(xs[((size_t)t * 64 + b) * Fd + j]);
      float si = sigm(iv), sf = sigm(fv), tg = tanhfast(gv), so = sigm(ov);
      float c = sf * xt + si * tg;
      float h = so * tanhfast(c);
      hbuf[(size_t)(t & 1) * (64 * 1024) + (size_t)b * 1024 + j] = f2bf(h);
      out[((size_t)b * 1024 + j) * Seq + t] = h;
      if (t == Seq - 1) {
        out[(size_t)16777216 + (size_t)b * 1024 + j] = h;
        out[(size_t)16777216 + 65536 + (size_t)b * 1024 + j] = c;
      }
    }
    __threadfence();   // release: flush h chunk to coherent point
    __syncthreads();   // all threads in block done + fenced
    if (tid == 0)
      __hip_atomic_store(mytag, (unsigned int)(t + 1), __ATOMIC_RELAXED,
                         __HIP_MEMORY_SCOPE_AGENT);
  }
}

extern "C" void kernel_launch(void* const* d_in, const int* in_sizes, int n_in,
                              void* d_out, int out_size, void* d_ws, size_t ws_size,
                              hipStream_t stream) {
  const float* x    = (const float*)d_in[0];
  const float* W    = (const float*)d_in[1];
  const float* U    = (const float*)d_in[2];
  const float* bias = (const float*)d_in[3];
  float* out = (float*)d_out;
  char* ws = (char*)d_ws;

  // workspace layout
  unsigned short* xs  = (unsigned short*)(ws);                       // 32 MB
  unsigned short* Wbt = (unsigned short*)(ws + (size_t)33554432);    // 8 MB
  unsigned short* Ubt = (unsigned short*)(ws + (size_t)41943040);    // 8 MB
  unsigned short* xWb = (unsigned short*)(ws + (size_t)50331648);    // 128 MB
  unsigned short* hbuf = (unsigned short*)(ws + (size_t)184549376);  // 256 KB
  unsigned int* tags   = (unsigned int*)(ws + (size_t)184811520);    // 1 KB

  k_tx<<<dim3(Seq / 32, Fd / 32, Bsz), 256, 0, stream>>>(x, xs);
  k_tw<<<dim3(G4 / 32, 1024 / 32), 256, 0, stream>>>(W, Wbt);
  k_tw<<<dim3(G4 / 32, 1024 / 32), 256, 0, stream>>>(U, Ubt);
  k_zero<<<1, 256, 0, stream>>>(tags, 256);
  k_gemm<<<dim3((Mrows / 128) * (G4 / 128)), 256, 0, stream>>>(xs, Wbt, xWb);
  k_rec<<<dim3(256), 256, 0, stream>>>(xs, xWb, Ubt, bias, hbuf, tags, out);
}

// Round 2
// 969.746 us; speedup vs baseline: 13.4094x; 13.4094x over previous
//
#include <hip/hip_runtime.h>
#include <hip/hip_bf16.h>

typedef float f32x4 __attribute__((ext_vector_type(4)));
typedef short short8 __attribute__((ext_vector_type(8)));
typedef __bf16 bf16x8 __attribute__((ext_vector_type(8)));

#define DI __device__ __forceinline__

// Problem sizes
constexpr int Bsz = 64;    // batch
constexpr int Fd  = 1024;  // features == hidden
constexpr int Seq = 256;
constexpr int G4  = 4096;  // 4*H
constexpr int Mrows = Seq * Bsz;  // 16384 GEMM rows, r = s*64 + b

DI float bf2f(unsigned short u) {
  union { unsigned int i; float f; } v; v.i = ((unsigned int)u) << 16; return v.f;
}
DI unsigned short f2bf(float f) {
  union { float ff; unsigned int i; } v; v.ff = f;
  unsigned int x = v.i;
  return (unsigned short)((x + 0x7fffu + ((x >> 16) & 1u)) >> 16);
}
DI float sigm(float x) { return 1.f / (1.f + __expf(-x)); }
DI float tanhfast(float x) {
  float e = __expf(-2.f * fabsf(x));
  float t = (1.f - e) / (1.f + e);
  return x < 0.f ? -t : t;
}
DI f32x4 mfma16(short8 a, short8 b, f32x4 c) {
  return __builtin_amdgcn_mfma_f32_16x16x32_bf16(
      __builtin_bit_cast(bf16x8, a), __builtin_bit_cast(bf16x8, b), c, 0, 0, 0);
}

// ---------- transpose x [B][F][S] f32 -> xs [S][B][F] bf16 (r = s*64+b major) ----------
__global__ void k_tx(const float* __restrict__ x, unsigned short* __restrict__ xs) {
  __shared__ float t[32][33];
  int b = blockIdx.z, f0 = blockIdx.y * 32, s0 = blockIdx.x * 32;
  int tx = threadIdx.x & 31, ty = threadIdx.x >> 5;  // ty 0..7
  const float* src = x + ((size_t)b * Fd + f0) * Seq + s0;
#pragma unroll
  for (int i = 0; i < 32; i += 8)
    t[ty + i][tx] = src[(size_t)(ty + i) * Seq + tx];
  __syncthreads();
#pragma unroll
  for (int i = 0; i < 32; i += 8) {
    int s = s0 + ty + i, f = f0 + tx;
    xs[((size_t)s * Bsz + b) * Fd + f] = f2bf(t[tx][ty + i]);
  }
}

// ---------- transpose-convert [1024][4096] f32 -> [4096][1024] bf16 ----------
__global__ void k_tw(const float* __restrict__ in, unsigned short* __restrict__ out) {
  __shared__ float t[32][33];
  int n0 = blockIdx.x * 32, k0 = blockIdx.y * 32;
  int tx = threadIdx.x & 31, ty = threadIdx.x >> 5;
#pragma unroll
  for (int i = 0; i < 32; i += 8)
    t[ty + i][tx] = in[(size_t)(k0 + ty + i) * G4 + n0 + tx];
  __syncthreads();
#pragma unroll
  for (int i = 0; i < 32; i += 8)
    out[(size_t)(n0 + ty + i) * 1024 + k0 + tx] = f2bf(t[tx][ty + i]);
}

__global__ void k_zero(unsigned int* p, int n) {
  int i = blockIdx.x * 256 + threadIdx.x;
  if (i < n) p[i] = 0u;
}

// ---------- GEMM: C[16384][4096] bf16 = A[16384][1024] x Bt[4096][1024]^T ----------
__launch_bounds__(256, 2)
__global__ void k_gemm(const unsigned short* __restrict__ A,
                       const unsigned short* __restrict__ Bt,
                       unsigned short* __restrict__ C) {
  __shared__ unsigned short a_lds[128 * 64];
  __shared__ unsigned short b_lds[128 * 64];
  int bid = blockIdx.x;
  int tm = bid & 127, tn = bid >> 7;  // 128 m-tiles, 32 n-tiles
  int tid = threadIdx.x, w = tid >> 6, l = tid & 63;
  int wm = w >> 1, wn = w & 1;
  f32x4 acc[4][4] = {};
  const unsigned short* Ab = A + (size_t)(tm * 128) * 1024;
  const unsigned short* Bb = Bt + (size_t)(tn * 128) * 1024;
  for (int kt = 0; kt < 16; ++kt) {
#pragma unroll
    for (int i = 0; i < 4; ++i) {
      int ci = tid + i * 256;     // 0..1023 16B chunks
      int row = ci >> 3;
      int kB = (ci & 7) * 16;     // byte offset in 128B row
      short8 va = *(const short8*)((const char*)(Ab + (size_t)row * 1024 + kt * 64) + kB);
      short8 vb = *(const short8*)((const char*)(Bb + (size_t)row * 1024 + kt * 64) + kB);
      int dst = row * 128 + (kB ^ ((row & 7) << 4));
      *(short8*)((char*)a_lds + dst) = va;
      *(short8*)((char*)b_lds + dst) = vb;
    }
    __syncthreads();
#pragma unroll
    for (int kb = 0; kb < 2; ++kb) {
      short8 af[4], bfv[4];
      int kByte = (kb * 32 + ((l >> 4) << 3)) * 2;
#pragma unroll
      for (int mi = 0; mi < 4; ++mi) {
        int row = wm * 64 + mi * 16 + (l & 15);
        af[mi] = *(const short8*)((const char*)a_lds + row * 128 + (kByte ^ ((row & 7) << 4)));
      }
#pragma unroll
      for (int ni = 0; ni < 4; ++ni) {
        int row = wn * 64 + ni * 16 + (l & 15);
        bfv[ni] = *(const short8*)((const char*)b_lds + row * 128 + (kByte ^ ((row & 7) << 4)));
      }
#pragma unroll
      for (int mi = 0; mi < 4; ++mi)
#pragma unroll
        for (int ni = 0; ni < 4; ++ni)
          acc[mi][ni] = mfma16(af[mi], bfv[ni], acc[mi][ni]);
    }
    __syncthreads();
  }
#pragma unroll
  for (int mi = 0; mi < 4; ++mi)
#pragma unroll
    for (int ni = 0; ni < 4; ++ni)
#pragma unroll
      for (int r = 0; r < 4; ++r) {
        int m = tm * 128 + wm * 64 + mi * 16 + ((l >> 4) << 2) + r;
        int n = tn * 128 + wn * 64 + ni * 16 + (l & 15);
        C[(size_t)m * G4 + n] = f2bf(acc[mi][ni][r]);
      }
}

// ---------- recurrence ----------
// 256 blocks: rg = bid&3 (16 batch rows), jg = bid>>2 (16 hidden cols).
// Communication: h chunks + tags via SYSTEM-scope (sc0 sc1, MALL-coherent)
// relaxed atomics. NO fences: write-through stores drained by s_waitcnt
// vmcnt(0) before the tag store; coherent loads always read MALL-fresh data.
// Everything else (xW, xs, U, out) stays on the normal cached path.
__launch_bounds__(256, 1)
__global__ void k_rec(const unsigned short* __restrict__ xs,
                      const unsigned short* __restrict__ xWb,
                      const unsigned short* __restrict__ Ubt,
                      const float* __restrict__ bias,
                      unsigned int* __restrict__ hbuf,  // [2][64][512] dwords (2 bf16 each)
                      unsigned int* tags,               // [4][64]
                      float* __restrict__ out) {
  __shared__ unsigned short h_lds[16 * 1024];  // 32KB, swizzled
  __shared__ float g_lds[16][64];              // 4KB [row][gate*16+jj]
  __shared__ float obuf[256][17];              // 17.4KB out staging (+1 pad)
  int bid = blockIdx.x;
  int rg = bid & 3, jg = bid >> 2;
  int j0 = jg * 16;
  int tid = threadIdx.x, w = tid >> 6, l = tid & 63;

  // preload U fragments: col n = w*1024 + j0 + (l&15), k = kb*32 + (l>>4)*8
  int ncol = w * 1024 + j0 + (l & 15);
  const unsigned short* Urow = Ubt + (size_t)ncol * 1024;
  short8 ufr[32];
#pragma unroll
  for (int kb = 0; kb < 32; ++kb)
    ufr[kb] = *(const short8*)(Urow + kb * 32 + ((l >> 4) << 3));
  float bias_l = bias[ncol];

  unsigned int* mytags = tags + rg * 64;
  unsigned int* mytag = mytags + jg;

  int row2 = tid >> 4, jj = tid & 15;
  int bb = rg * 16 + row2, j = j0 + jj;

  for (int t = 0; t < Seq; ++t) {
    // ---- prefetch xW and x_t (plain cached loads; latency hides under spin)
    float xw[4];
#pragma unroll
    for (int r = 0; r < 4; ++r) {
      int m = rg * 16 + ((l >> 4) << 2) + r;
      xw[r] = bf2f(xWb[((size_t)t * 64 + m) * G4 + ncol]);
    }
    float xt = bf2f(xs[((size_t)t * 64 + bb) * Fd + j]);

    f32x4 acc = {0.f, 0.f, 0.f, 0.f};
    if (t > 0) {
      // ---- wait for all 64 producers of this rowgroup
      if (tid < 64) {
        while (__hip_atomic_load(&mytags[tid], __ATOMIC_RELAXED,
                                 __HIP_MEMORY_SCOPE_SYSTEM) < (unsigned int)t) {}
      }
      __syncthreads();
      // ---- coherent read of h(t-1): 8192 dwords -> LDS (swizzled)
      const unsigned int* hprev = hbuf + (((t & 1) ^ 1) << 15) + (rg << 13);
      unsigned int hv[32];
#pragma unroll
      for (int i = 0; i < 32; ++i)
        hv[i] = __hip_atomic_load(hprev + tid + i * 256, __ATOMIC_RELAXED,
                                  __HIP_MEMORY_SCOPE_SYSTEM);
#pragma unroll
      for (int i = 0; i < 32; ++i) {
        int ci = tid + i * 256;
        int row = ci >> 9, kB = (ci & 511) * 4;
        *(unsigned int*)((char*)h_lds + row * 2048 + (kB ^ ((row & 7) << 4))) = hv[i];
      }
      __syncthreads();
      // ---- gates = h @ U (wave w = gate w, 16x16 tile, K=1024)
#pragma unroll
      for (int kb = 0; kb < 32; ++kb) {
        int row = l & 15;
        int kByte = (kb * 32 + ((l >> 4) << 3)) * 2;
        short8 af = *(const short8*)((const char*)h_lds + row * 2048 +
                                     (kByte ^ ((row & 7) << 4)));
        acc = mfma16(af, ufr[kb], acc);
      }
    }
    // ---- gates -> LDS (add xW + bias)
#pragma unroll
    for (int r = 0; r < 4; ++r)
      g_lds[((l >> 4) << 2) + r][w * 16 + (l & 15)] = acc[r] + xw[r] + bias_l;
    __syncthreads();
    // ---- pointwise: thread = (row2, jj)
    float iv = g_lds[row2][jj];
    float fv = g_lds[row2][16 + jj];
    float gv = g_lds[row2][32 + jj];
    float ov = g_lds[row2][48 + jj];
    float si = sigm(iv), sf = sigm(fv), tg = tanhfast(gv), so = sigm(ov);
    float c = sf * xt + si * tg;
    float h = so * tanhfast(c);
    // ---- publish h (coherent, packed 2x bf16 per dword, even-jj lanes store)
    unsigned short hb = f2bf(h);
    unsigned int other = (unsigned int)(unsigned short)__shfl_xor((int)(unsigned int)hb, 1);
    if ((jj & 1) == 0) {
      unsigned int u = (unsigned int)hb | (other << 16);
      __hip_atomic_store(hbuf + ((t & 1) << 15) + (bb << 9) + (j >> 1), u,
                         __ATOMIC_RELAXED, __HIP_MEMORY_SCOPE_SYSTEM);
    }
    // ---- stage output in LDS (own row, no barrier needed)
    obuf[tid][t & 15] = h;
    if (t == Seq - 1) {
      out[(size_t)16777216 + (size_t)bb * 1024 + j] = h;
      out[(size_t)16777216 + 65536 + (size_t)bb * 1024 + j] = c;
    }
    // ---- release: drain write-through stores, then bump tag
    asm volatile("s_waitcnt vmcnt(0)" ::: "memory");
    __syncthreads();
    if (tid == 0)
      __hip_atomic_store(mytag, (unsigned int)(t + 1), __ATOMIC_RELAXED,
                         __HIP_MEMORY_SCOPE_SYSTEM);
    // ---- off critical path: coalesced out flush every 16 steps
    if ((t & 15) == 15) {
      float* dst = out + ((size_t)bb * 1024 + j) * Seq + (t - 15);
#pragma unroll
      for (int q = 0; q < 4; ++q) {
        f32x4 v = {obuf[tid][q * 4], obuf[tid][q * 4 + 1],
                   obuf[tid][q * 4 + 2], obuf[tid][q * 4 + 3]};
        *(f32x4*)(dst + q * 4) = v;
      }
    }
  }
}

extern "C" void kernel_launch(void* const* d_in, const int* in_sizes, int n_in,
                              void* d_out, int out_size, void* d_ws, size_t ws_size,
                              hipStream_t stream) {
  const float* x    = (const float*)d_in[0];
  const float* W    = (const float*)d_in[1];
  const float* U    = (const float*)d_in[2];
  const float* bias = (const float*)d_in[3];
  float* out = (float*)d_out;
  char* ws = (char*)d_ws;

  // workspace layout
  unsigned short* xs  = (unsigned short*)(ws);                       // 32 MB
  unsigned short* Wbt = (unsigned short*)(ws + (size_t)33554432);    // 8 MB
  unsigned short* Ubt = (unsigned short*)(ws + (size_t)41943040);    // 8 MB
  unsigned short* xWb = (unsigned short*)(ws + (size_t)50331648);    // 128 MB
  unsigned int* hbuf  = (unsigned int*)(ws + (size_t)184549376);     // 256 KB
  unsigned int* tags  = (unsigned int*)(ws + (size_t)184811520);     // 1 KB

  k_tx<<<dim3(Seq / 32, Fd / 32, Bsz), 256, 0, stream>>>(x, xs);
  k_tw<<<dim3(G4 / 32, 1024 / 32), 256, 0, stream>>>(W, Wbt);
  k_tw<<<dim3(G4 / 32, 1024 / 32), 256, 0, stream>>>(U, Ubt);
  k_zero<<<1, 256, 0, stream>>>(tags, 256);
  k_gemm<<<dim3((Mrows / 128) * (G4 / 128)), 256, 0, stream>>>(xs, Wbt, xWb);
  k_rec<<<dim3(256), 256, 0, stream>>>(xs, xWb, Ubt, bias, hbuf, tags, out);
}